// Round 9
// baseline (18845.071 us; speedup 1.0000x reference)
//
#include <hip/hip_runtime.h>
#include <cstdint>
#include <cstddef>

namespace {
constexpr int T_ = 500, S_ = 32, B_ = 128, L_ = 64, R_ = 8;

__device__ __forceinline__ float rdlane(float v, int l) {
  return __int_as_float(__builtin_amdgcn_readlane(__float_as_int(v), l));
}
template<int CTRL, int RM>
__device__ __forceinline__ float dppadd(float v) {
  int t = __builtin_amdgcn_update_dpp(0, __float_as_int(v), CTRL, RM, 0xf, false);
  return v + __int_as_float(t);
}
// full 64-lane sum; total lands in lane 63 (VALU-only, no DS)
__device__ __forceinline__ float wredsum(float v) {
  v = dppadd<0x111, 0xf>(v);   // row_shr:1
  v = dppadd<0x112, 0xf>(v);   // row_shr:2
  v = dppadd<0x114, 0xf>(v);   // row_shr:4
  v = dppadd<0x118, 0xf>(v);   // row_shr:8
  v = dppadd<0x142, 0xa>(v);   // row_bcast:15 -> rows 1,3
  v = dppadd<0x143, 0xc>(v);   // row_bcast:31 -> rows 2,3
  return v;
}
__device__ __forceinline__ float wsum(float v) {  // all-lanes result (step0 only)
  v += __shfl_xor(v, 1);  v += __shfl_xor(v, 2);  v += __shfl_xor(v, 4);
  v += __shfl_xor(v, 8);  v += __shfl_xor(v, 16); v += __shfl_xor(v, 32);
  return v;
}
__device__ __forceinline__ void gload16(const float* g, float* l) {
  __builtin_amdgcn_global_load_lds((const __attribute__((address_space(1))) uint32_t*)g,
                                   (__attribute__((address_space(3))) uint32_t*)l,
                                   16, 0, 0);
}
// barrier that drains LDS ops but lets global loads/stores ride (vmcnt untouched)
__device__ __forceinline__ void bar_lgkm() {
  asm volatile("s_waitcnt lgkmcnt(0)\n\ts_barrier" ::: "memory");
}
}  // namespace

// One block per batch element b. 1024 threads = 16 waves (4/SIMD for latency
// hiding); wave w owns ensemble rows {2w, 2w+1}. Serial tails specialized:
// wave0 = u/t8 (published via LDS), wave1 = 8x8 Cholesky, wave2 = mf tail.
__global__ __launch_bounds__(1024, 1) void nlf_kernel(
    const float* __restrict__ m0p, const float* __restrict__ q0p,
    const float* __restrict__ qp,  const float* __restrict__ kp,
    const float* __restrict__ Kp,  const float* __restrict__ Ap,
    const float* __restrict__ wp0p, const float* __restrict__ wf0p,
    const float* __restrict__ wp1p, const float* __restrict__ wp2p,
    const float* __restrict__ wfp,  float* __restrict__ outp)
{
  __shared__ __align__(16) float z_s[S_*68];      // carry z' (z - mf)
  __shared__ __align__(16) float Mc_s[L_*33];     // M_c[l][s]
  __shared__ __align__(16) float uni[16*68];      // mp partial sums
  __shared__ __align__(16) float wp1b[2][S_*S_];
  __shared__ __align__(16) float wp2b[2][S_*L_];
  __shared__ __align__(16) float wf_s[S_*R_];
  __shared__ __align__(16) float Kt_s[L_*R_];
  __shared__ __align__(16) float v1t_s[S_*R_];
  __shared__ __align__(16) float KM_s[S_*R_];     // [s*8+r]
  __shared__ __align__(16) float M8_s[64];
  __shared__ __align__(16) float C8_s[64];
  __shared__ __align__(16) float tk_s[S_];        // Mc^T k_t
  __shared__ __align__(16) float t8_s[8];         // K^T u (wave0 -> wave2)
  __shared__ __align__(16) float u_s[L_];         // u vector (wave0 -> wave2)
  __shared__ __align__(16) float mf_s[L_];
  __shared__ __align__(16) float qv_s[L_];
  __shared__ __align__(16) float q0v_s[L_];

  const int tid = threadIdx.x;
  const int lam = tid & 63;
  const int w   = tid >> 6;
  const int b   = blockIdx.x;

  float Areg[64];
#pragma unroll
  for (int j4 = 0; j4 < 16; ++j4) {
    float4 a4 = *(const float4*)(Ap + (size_t)lam*64 + j4*4);
    Areg[4*j4+0]=a4.x; Areg[4*j4+1]=a4.y; Areg[4*j4+2]=a4.z; Areg[4*j4+3]=a4.w;
  }
  const float q_r  = qp[lam];
  const float qs_r = sqrtf(q_r);
  const float q0_r = q0p[lam];
  const float m0_r = m0p[lam];
  if (tid < 64) { qv_s[tid] = q_r; q0v_s[tid] = q0_r; }

  float Kreg[8];
  {
    const float* kb = Kp + (size_t)b*(L_*R_) + lam*R_;
    float4 ka = *(const float4*)kb, kb4 = *(const float4*)(kb+4);
    Kreg[0]=ka.x;Kreg[1]=ka.y;Kreg[2]=ka.z;Kreg[3]=ka.w;
    Kreg[4]=kb4.x;Kreg[5]=kb4.y;Kreg[6]=kb4.z;Kreg[7]=kb4.w;
  }
  float kt_r = kp[(size_t)b*L_ + lam];

  // ---- prologue async loads ----
  if (w == 0) {                       // wp1[0] -> wp1b[1]
#pragma unroll
    for (int m = 0; m < 4; ++m) {
      int f = m*256 + lam*4, s = f >> 5, c = f & 31;
      gload16(wp1p + ((size_t)s*B_ + b)*S_ + c, &wp1b[1][f]);
    }
  } else if (w == 1 || w == 2) {      // wp2[0] -> wp2b[1]
#pragma unroll
    for (int m = 0; m < 4; ++m) {
      int f = (w-1)*1024 + m*256 + lam*4, s = f >> 6, c = f & 63;
      gload16(wp2p + ((size_t)s*B_ + b)*L_ + c, &wp2b[1][f]);
    }
  } else if (w == 3) {                // wf0 -> wf_s ; K[0] -> Kt_s
    { int f = lam*4, s = f >> 3, c = f & 7;
      gload16(wf0p + ((size_t)s*B_ + b)*R_ + c, &wf_s[f]); }
#pragma unroll
    for (int m = 0; m < 2; ++m) {
      int f = m*256 + lam*4;
      gload16(Kp + (size_t)b*(L_*R_) + f, &Kt_s[f]);
    }
  } else if (w == 4 || w == 5) {      // w_p0 -> wp2b[0]
#pragma unroll
    for (int m = 0; m < 4; ++m) {
      int f = (w-4)*1024 + m*256 + lam*4, s = f >> 6, c = f & 63;
      gload16(wp0p + ((size_t)s*B_ + b)*L_ + c, &wp2b[0][f]);
    }
  }
  __syncthreads();

  // 8x8 SPD: C8_s -> M8_s = inv(C8) via in-register Cholesky (rows in lanes 0-7)
  auto chol8M8 = [&]() {
    const int i8 = lam & 7;
    float c8[8], rd8 = 0.0f;
#pragma unroll
    for (int k = 0; k < 8; ++k) c8[k] = C8_s[i8*8 + k];
#pragma unroll
    for (int j = 0; j < 8; ++j) {
      float dj = rdlane(c8[j], j);
      float rinv = rsqrtf(dj);
      if (i8 == j) rd8 = rinv;
      c8[j] *= rinv;
#pragma unroll
      for (int k = j+1; k < 8; ++k)
        c8[k] = fmaf(-rdlane(c8[j], k), c8[j], c8[k]);
    }
    float w8[8];
#pragma unroll
    for (int i = 0; i < 8; ++i) {
      float sacc = (i == i8) ? 1.0f : 0.0f;
#pragma unroll
      for (int k = 0; k < i; ++k)
        sacc = fmaf(-rdlane(c8[k], i), w8[k], sacc);
      w8[i] = sacc * rdlane(rd8, i);
    }
#pragma unroll
    for (int i = 0; i < 8; ++i) {
      float msum = 0.0f;
#pragma unroll
      for (int k = 0; k < 8; ++k)
        msum = fmaf(rdlane(w8[k], i), w8[k], msum);
      if (lam < 8) M8_s[i*8 + lam] = msum;
    }
  };

  // ================= step 0 =================
  {
    const float Pp = q0_r;
    const float h0 = m0_r / Pp + kt_r;
    if (w == 0) {
      const int r1 = lam >> 3, r2 = lam & 7;
      float acc = 0.0f;
#pragma unroll 4
      for (int l = 0; l < 64; ++l)
        acc = fmaf(Kt_s[l*8 + r1] * q0v_s[l], Kt_s[l*8 + r2], acc);
      C8_s[lam] = acc + (r1 == r2 ? 1.0f : 0.0f);
      chol8M8();
      float t8[8];
#pragma unroll
      for (int r = 0; r < 8; ++r) t8[r] = wsum(Pp * Kreg[r] * h0);
      float acc2 = 0.0f;
#pragma unroll
      for (int r1i = 0; r1i < 8; ++r1i) {
        float4 ma = *(const float4*)&M8_s[r1i*8];
        float4 mb = *(const float4*)&M8_s[r1i*8+4];
        float y = ma.x*t8[0]+ma.y*t8[1]+ma.z*t8[2]+ma.w*t8[3]
                + mb.x*t8[4]+mb.y*t8[5]+mb.z*t8[6]+mb.w*t8[7];
        acc2 = fmaf(Kreg[r1i], y, acc2);
      }
      float m0f = Pp*h0 - Pp*acc2;
      mf_s[lam] = m0f;
      outp[(size_t)b*L_ + lam] = m0f;
    }
    __syncthreads();

    const float qs0 = sqrtf(q0_r);
#pragma unroll
    for (int i = 0; i < 2; ++i) {
      const int s = 2*w + i;
      float zp = qs0 * wp2b[0][s*64 + lam];
      float v1[8];
#pragma unroll
      for (int r = 0; r < 8; ++r)
        v1[r] = wsum(Kreg[r] * zp) + wf_s[s*8 + r];
      float acc = 0.0f;
#pragma unroll
      for (int r1i = 0; r1i < 8; ++r1i) {
        float4 ma = *(const float4*)&M8_s[r1i*8];
        float4 mb = *(const float4*)&M8_s[r1i*8+4];
        float y = ma.x*v1[0]+ma.y*v1[1]+ma.z*v1[2]+ma.w*v1[3]
                + mb.x*v1[4]+mb.y*v1[5]+mb.z*v1[6]+mb.w*v1[7];
        acc = fmaf(Kreg[r1i], y, acc);
      }
      z_s[s*68 + lam] = zp - Pp*acc;   // z' excludes m_f (added in next dyn)
    }
  }
  __syncthreads();

  // ================= steps 1..T-1 =================
  for (int t = 1; t < T_; ++t) {
    const int cb = t & 1, nb = cb ^ 1;

    // per-lane K/k reload (global; hidden under P1, used from P2 on)
    {
      const float* kb = Kp + ((size_t)t*B_ + b)*(L_*R_) + lam*R_;
      float4 ka = *(const float4*)kb, kb4 = *(const float4*)(kb+4);
      Kreg[0]=ka.x;Kreg[1]=ka.y;Kreg[2]=ka.z;Kreg[3]=ka.w;
      Kreg[4]=kb4.x;Kreg[5]=kb4.y;Kreg[6]=kb4.z;Kreg[7]=kb4.w;
      kt_r = kp[((size_t)t*B_ + b)*L_ + lam];
    }

    // ---- P1: dyn on z = z' + mf (rows via conflict-free b128 broadcasts) ----
    float dmf = 0.0f;
#pragma unroll
    for (int j4 = 0; j4 < 16; ++j4) {
      float4 m4 = *(const float4*)&mf_s[4*j4];
      dmf = fmaf(m4.x, Areg[4*j4+0], dmf);
      dmf = fmaf(m4.y, Areg[4*j4+1], dmf);
      dmf = fmaf(m4.z, Areg[4*j4+2], dmf);
      dmf = fmaf(m4.w, Areg[4*j4+3], dmf);
    }
    const float mfl = mf_s[lam];
    float zn[2];
#pragma unroll
    for (int i = 0; i < 2; ++i) {
      const int s = 2*w + i;
      float a0=0,a1=0,a2=0,a3=0;
#pragma unroll
      for (int j4 = 0; j4 < 16; ++j4) {
        float4 zb = *(const float4*)&z_s[s*68 + 4*j4];
        a0 = fmaf(zb.x, Areg[4*j4+0], a0);
        a1 = fmaf(zb.y, Areg[4*j4+1], a1);
        a2 = fmaf(zb.z, Areg[4*j4+2], a2);
        a3 = fmaf(zb.w, Areg[4*j4+3], a3);
      }
      float x = ((a0+a1)+(a2+a3)) + dmf;
      float e = __expf(2.0f*x);
      float tnh = 1.0f - 2.0f/(e + 1.0f);
      zn[i] = (z_s[s*68 + lam] + mfl) + 0.1f*tnh;
    }
    uni[w*68 + lam] = zn[0]+zn[1];
    bar_lgkm();  // B1

    // ---- P0: async prefetch; drains at B2 (syncthreads) ----
    if (w == 0) {
      if (t < T_-1) {
#pragma unroll
        for (int m = 0; m < 4; ++m) {
          int f = m*256 + lam*4, s = f >> 5, c = f & 31;
          gload16(wp1p + (((size_t)t*S_ + s)*B_ + b)*S_ + c, &wp1b[nb][f]);
        }
      }
    } else if (w == 1 || w == 2) {
      if (t < T_-1) {
#pragma unroll
        for (int m = 0; m < 4; ++m) {
          int f = (w-1)*1024 + m*256 + lam*4, s = f >> 6, c = f & 63;
          gload16(wp2p + (((size_t)t*S_ + s)*B_ + b)*L_ + c, &wp2b[nb][f]);
        }
      }
    } else if (w == 3) {
      { int f = lam*4, s = f >> 3, c = f & 7;
        gload16(wfp + (((size_t)(t-1)*S_ + s)*B_ + b)*R_ + c, &wf_s[f]); }
#pragma unroll
      for (int m = 0; m < 2; ++m) {
        int f = m*256 + lam*4;
        gload16(Kp + ((size_t)t*B_ + b)*(L_*R_) + f, &Kt_s[f]);
      }
    }

    // ---- P2: m_p, M_c, KM = K^T Mc, tk = Mc^T k_t (DPP) ----
    float mp = 0.0f;
#pragma unroll
    for (int ww = 0; ww < 16; ++ww) mp += uni[ww*68 + lam];
    mp *= 0.03125f;
    float mcv[2];
#pragma unroll
    for (int i = 0; i < 2; ++i) {
      const int s = 2*w + i;
      mcv[i] = (zn[i] - mp) * 0.17677669529663689f;
      Mc_s[lam*33 + s] = mcv[i];
      float tkv = wredsum(mcv[i] * kt_r);
      float kmv[8];
#pragma unroll
      for (int r = 0; r < 8; ++r) kmv[r] = wredsum(mcv[i] * Kreg[r]);
      if (lam == 63) {
        tk_s[s] = tkv;
        *(float4*)&KM_s[s*8]   = make_float4(kmv[0],kmv[1],kmv[2],kmv[3]);
        *(float4*)&KM_s[s*8+4] = make_float4(kmv[4],kmv[5],kmv[6],kmv[7]);
      }
    }
    __syncthreads();  // B2 (full: drains prefetch vmcnt)

    // per-lane Mc row into registers (reused by P3 and P4)
    float mcrow[32];
#pragma unroll
    for (int s2 = 0; s2 < 32; ++s2) mcrow[s2] = Mc_s[lam*33 + s2];

    // ---- P3: 2 zprows/wave + wave0 {u,t8 -> LDS} + wave1 {C8, M8} ----
    float zloc[2];
#pragma unroll
    for (int i = 0; i < 2; ++i) {
      const int s = 2*w + i;
      float acc = 0.0f;
#pragma unroll
      for (int p4 = 0; p4 < 32; p4 += 4) {
        float4 wb = *(const float4*)&wp1b[cb][s*32 + p4];
        acc = fmaf(mcrow[p4+0], wb.x, acc);
        acc = fmaf(mcrow[p4+1], wb.y, acc);
        acc = fmaf(mcrow[p4+2], wb.z, acc);
        acc = fmaf(mcrow[p4+3], wb.w, acc);
      }
      float zp = acc + qs_r * wp2b[cb][s*64 + lam];
      zloc[i] = zp;
      float vv[8];
#pragma unroll
      for (int r = 0; r < 8; ++r) vv[r] = wredsum(Kreg[r] * zp);
      if (lam == 63) {
        float4 wfa = *(const float4*)&wf_s[s*8];
        float4 wfb = *(const float4*)&wf_s[s*8+4];
        *(float4*)&v1t_s[s*8]   = make_float4(vv[0]+wfa.x, vv[1]+wfa.y,
                                              vv[2]+wfa.z, vv[3]+wfa.w);
        *(float4*)&v1t_s[s*8+4] = make_float4(vv[4]+wfb.x, vv[5]+wfb.y,
                                              vv[6]+wfb.z, vv[7]+wfb.w);
      }
    }
    if (w == 0) {
      // u = m_p + Mc tk + q k_t (Woodbury); t8 = K^T u; publish to LDS
      float mctk = 0.0f;
#pragma unroll
      for (int s4 = 0; s4 < 32; s4 += 4) {
        float4 tb = *(const float4*)&tk_s[s4];
        mctk = fmaf(mcrow[s4+0], tb.x, mctk);
        mctk = fmaf(mcrow[s4+1], tb.y, mctk);
        mctk = fmaf(mcrow[s4+2], tb.z, mctk);
        mctk = fmaf(mcrow[s4+3], tb.w, mctk);
      }
      float u_r = mp + mctk + q_r * kt_r;
      u_s[lam] = u_r;
      float vv[8];
#pragma unroll
      for (int r = 0; r < 8; ++r) vv[r] = wredsum(Kreg[r] * u_r);
      if (lam == 63) {
        *(float4*)&t8_s[0] = make_float4(vv[0],vv[1],vv[2],vv[3]);
        *(float4*)&t8_s[4] = make_float4(vv[4],vv[5],vv[6],vv[7]);
      }
    } else if (w == 1) {
      const int r1 = lam >> 3, r2 = lam & 7;
      float acc = 0.0f;
#pragma unroll 4
      for (int s = 0; s < 32; ++s)
        acc = fmaf(KM_s[s*8 + r1], KM_s[s*8 + r2], acc);
#pragma unroll 4
      for (int l = 0; l < 64; ++l)
        acc = fmaf(Kt_s[l*8 + r1] * qv_s[l], Kt_s[l*8 + r2], acc);
      C8_s[lam] = acc + (r1 == r2 ? 1.0f : 0.0f);
      chol8M8();
    }
    bar_lgkm();  // B3 (M8_s, v1t_s, u_s, t8_s visible)

    // ---- P4: per-row y1/g + corr; wave2 additionally mf tail ----
    float gg[2];
#pragma unroll
    for (int i = 0; i < 2; ++i) {
      const int s = 2*w + i;
      float4 va = *(const float4*)&v1t_s[s*8];
      float4 vb = *(const float4*)&v1t_s[s*8+4];
      float g = 0.0f;
#pragma unroll
      for (int r1i = 0; r1i < 8; ++r1i) {
        float4 ma = *(const float4*)&M8_s[r1i*8];
        float4 mb = *(const float4*)&M8_s[r1i*8+4];
        float y = ma.x*va.x+ma.y*va.y+ma.z*va.z+ma.w*va.w
                + mb.x*vb.x+mb.y*vb.y+mb.z*vb.z+mb.w*vb.w;
        g = fmaf(Kreg[r1i], y, g);
      }
      gg[i] = g;
    }
    if (w == 2) {
      // gv = K M8 t8 (from LDS); fused 3-accumulator corr loop
      float4 ta = *(const float4*)&t8_s[0];
      float4 tb = *(const float4*)&t8_s[4];
      float gvv = 0.0f;
#pragma unroll
      for (int r1i = 0; r1i < 8; ++r1i) {
        float4 ma = *(const float4*)&M8_s[r1i*8];
        float4 mb = *(const float4*)&M8_s[r1i*8+4];
        float y = ma.x*ta.x+ma.y*ta.y+ma.z*ta.z+ma.w*ta.w
                + mb.x*tb.x+mb.y*tb.y+mb.z*tb.z+mb.w*tb.w;
        gvv = fmaf(Kreg[r1i], y, gvv);
      }
      float c0=0.0f, c1=0.0f, cm=0.0f;
#pragma unroll
      for (int s2 = 0; s2 < 32; ++s2) {
        const float mcl = mcrow[s2];
        float a0 = wredsum(mcl * gg[0]);
        float a1 = wredsum(mcl * gg[1]);
        float am = wredsum(mcl * gvv);
        c0 = fmaf(mcl, rdlane(a0, 63), c0);
        c1 = fmaf(mcl, rdlane(a1, 63), c1);
        cm = fmaf(mcl, rdlane(am, 63), cm);
      }
      const int sb = 2*w;
      z_s[(sb+0)*68 + lam] = zloc[0] - c0 - q_r*gg[0];
      z_s[(sb+1)*68 + lam] = zloc[1] - c1 - q_r*gg[1];
      const float mf_r = u_s[lam] - cm - q_r*gvv;
      mf_s[lam] = mf_r;
      outp[((size_t)t*B_ + b)*L_ + lam] = mf_r;
    } else {
      float c0=0.0f, c1=0.0f;
#pragma unroll
      for (int s2 = 0; s2 < 32; ++s2) {
        const float mcl = mcrow[s2];
        float a0 = wredsum(mcl * gg[0]);
        float a1 = wredsum(mcl * gg[1]);
        c0 = fmaf(mcl, rdlane(a0, 63), c0);
        c1 = fmaf(mcl, rdlane(a1, 63), c1);
      }
      const int sb = 2*w;
      z_s[(sb+0)*68 + lam] = zloc[0] - c0 - q_r*gg[0];
      z_s[(sb+1)*68 + lam] = zloc[1] - c1 - q_r*gg[1];
    }
    bar_lgkm();  // B4 (mf_s, z_s visible for next P1)
  }
}

extern "C" void kernel_launch(void* const* d_in, const int* in_sizes, int n_in,
                              void* d_out, int out_size, void* d_ws, size_t ws_size,
                              hipStream_t stream) {
  (void)in_sizes; (void)n_in; (void)out_size; (void)d_ws; (void)ws_size;
  nlf_kernel<<<dim3(B_), dim3(1024), 0, stream>>>(
      (const float*)d_in[0], (const float*)d_in[1], (const float*)d_in[2],
      (const float*)d_in[3], (const float*)d_in[4], (const float*)d_in[5],
      (const float*)d_in[6], (const float*)d_in[7], (const float*)d_in[8],
      (const float*)d_in[9], (const float*)d_in[10], (float*)d_out);
}

// Round 10
// 16901.764 us; speedup vs baseline: 1.1150x; 1.1150x over previous
//
#include <hip/hip_runtime.h>
#include <cstdint>
#include <cstddef>

namespace {
constexpr int T_ = 500, S_ = 32, B_ = 128, L_ = 64, R_ = 8;

__device__ __forceinline__ float rdlane(float v, int l) {
  return __int_as_float(__builtin_amdgcn_readlane(__float_as_int(v), l));
}
template<int CTRL, int RM>
__device__ __forceinline__ float dppadd(float v) {
  int t = __builtin_amdgcn_update_dpp(0, __float_as_int(v), CTRL, RM, 0xf, false);
  return v + __int_as_float(t);
}
// full 64-lane sum; total lands in lane 63 (VALU-only, no DS)
__device__ __forceinline__ float wredsum(float v) {
  v = dppadd<0x111, 0xf>(v);   // row_shr:1
  v = dppadd<0x112, 0xf>(v);   // row_shr:2
  v = dppadd<0x114, 0xf>(v);   // row_shr:4
  v = dppadd<0x118, 0xf>(v);   // row_shr:8
  v = dppadd<0x142, 0xa>(v);   // row_bcast:15 -> rows 1,3
  v = dppadd<0x143, 0xc>(v);   // row_bcast:31 -> rows 2,3
  return v;
}
__device__ __forceinline__ float wsum(float v) {  // all-lanes result (step0 only)
  v += __shfl_xor(v, 1);  v += __shfl_xor(v, 2);  v += __shfl_xor(v, 4);
  v += __shfl_xor(v, 8);  v += __shfl_xor(v, 16); v += __shfl_xor(v, 32);
  return v;
}
__device__ __forceinline__ void gload16(const float* g, float* l) {
  __builtin_amdgcn_global_load_lds((const __attribute__((address_space(1))) uint32_t*)g,
                                   (__attribute__((address_space(3))) uint32_t*)l,
                                   16, 0, 0);
}
// barrier that drains LDS ops but lets global loads/stores ride (vmcnt untouched)
__device__ __forceinline__ void bar_lgkm() {
  asm volatile("s_waitcnt lgkmcnt(0)\n\ts_barrier" ::: "memory");
}
}  // namespace

// One block per batch element b. 512 threads = 8 waves (block=512 -> compiler
// allocates 128 VGPRs; 1024 -> 64 and catastrophic spills, measured R9).
// Key identity this round: Mc(Mc^T(K y)) = MKM y with mkm[r] =
// sum_s2 Mc[lam][s2]*KM[s2][r] (KM = Mc^T K already computed in P2) ->
// every per-row 32-wredsum correction loop collapses to 8 FMA.
__global__ __launch_bounds__(512, 1) void nlf_kernel(
    const float* __restrict__ m0p, const float* __restrict__ q0p,
    const float* __restrict__ qp,  const float* __restrict__ kp,
    const float* __restrict__ Kp,  const float* __restrict__ Ap,
    const float* __restrict__ wp0p, const float* __restrict__ wf0p,
    const float* __restrict__ wp1p, const float* __restrict__ wp2p,
    const float* __restrict__ wfp,  float* __restrict__ outp)
{
  __shared__ __align__(16) float z_s[S_*68];      // carry z' (z - mf)
  __shared__ __align__(16) float Mc_s[L_*33];     // M_c[l][s]
  __shared__ __align__(16) float uni[8*68];       // mp partial sums
  __shared__ __align__(16) float wp1b[2][S_*S_];
  __shared__ __align__(16) float wp2b[2][S_*L_];
  __shared__ __align__(16) float wf_s[S_*R_];
  __shared__ __align__(16) float Kt_s[L_*R_];
  __shared__ __align__(16) float v1t_s[S_*R_];
  __shared__ __align__(16) float KM_s[S_*R_];     // [s*8+r] = (Mc^T K)[s][r]
  __shared__ __align__(16) float M8_s[64];
  __shared__ __align__(16) float C8_s[64];
  __shared__ __align__(16) float tk_s[S_];        // Mc^T k_t
  __shared__ __align__(16) float mf_s[L_];
  __shared__ __align__(16) float qv_s[L_];
  __shared__ __align__(16) float q0v_s[L_];

  const int tid = threadIdx.x;
  const int lam = tid & 63;
  const int w   = tid >> 6;
  const int b   = blockIdx.x;

  // row ownership: waves 0,1 have 3 rows (+specials), 2-5 have 4, 6-7 have 5
  const int rstart = (w <= 1) ? 3*w : ((w <= 6) ? 6 + 4*(w-2) : 27);
  const int rcount = (w <= 1) ? 3 : ((w >= 6) ? 5 : 4);

  float Areg[64];
#pragma unroll
  for (int j4 = 0; j4 < 16; ++j4) {
    float4 a4 = *(const float4*)(Ap + (size_t)lam*64 + j4*4);
    Areg[4*j4+0]=a4.x; Areg[4*j4+1]=a4.y; Areg[4*j4+2]=a4.z; Areg[4*j4+3]=a4.w;
  }
  const float q_r  = qp[lam];
  const float qs_r = sqrtf(q_r);
  const float q0_r = q0p[lam];
  const float m0_r = m0p[lam];
  if (tid < 64) { qv_s[tid] = q_r; q0v_s[tid] = q0_r; }

  float Kreg[8];
  {
    const float* kb = Kp + (size_t)b*(L_*R_) + lam*R_;
    float4 ka = *(const float4*)kb, kb4 = *(const float4*)(kb+4);
    Kreg[0]=ka.x;Kreg[1]=ka.y;Kreg[2]=ka.z;Kreg[3]=ka.w;
    Kreg[4]=kb4.x;Kreg[5]=kb4.y;Kreg[6]=kb4.z;Kreg[7]=kb4.w;
  }
  float kt_r = kp[(size_t)b*L_ + lam];

  // ---- prologue async loads ----
  if (w == 0) {                       // wp1[0] -> wp1b[1]
#pragma unroll
    for (int m = 0; m < 4; ++m) {
      int f = m*256 + lam*4, s = f >> 5, c = f & 31;
      gload16(wp1p + ((size_t)s*B_ + b)*S_ + c, &wp1b[1][f]);
    }
  } else if (w == 1 || w == 2) {      // wp2[0] -> wp2b[1]
#pragma unroll
    for (int m = 0; m < 4; ++m) {
      int f = (w-1)*1024 + m*256 + lam*4, s = f >> 6, c = f & 63;
      gload16(wp2p + ((size_t)s*B_ + b)*L_ + c, &wp2b[1][f]);
    }
  } else if (w == 3) {                // wf0 -> wf_s ; K[0] -> Kt_s
    { int f = lam*4, s = f >> 3, c = f & 7;
      gload16(wf0p + ((size_t)s*B_ + b)*R_ + c, &wf_s[f]); }
#pragma unroll
    for (int m = 0; m < 2; ++m) {
      int f = m*256 + lam*4;
      gload16(Kp + (size_t)b*(L_*R_) + f, &Kt_s[f]);
    }
  } else if (w == 4 || w == 5) {      // w_p0 -> wp2b[0]
#pragma unroll
    for (int m = 0; m < 4; ++m) {
      int f = (w-4)*1024 + m*256 + lam*4, s = f >> 6, c = f & 63;
      gload16(wp0p + ((size_t)s*B_ + b)*L_ + c, &wp2b[0][f]);
    }
  }
  __syncthreads();

  // 8x8 SPD: C8_s -> M8_s = inv(C8) via in-register Cholesky (rows in lanes 0-7)
  auto chol8M8 = [&]() {
    const int i8 = lam & 7;
    float c8[8], rd8 = 0.0f;
#pragma unroll
    for (int k = 0; k < 8; ++k) c8[k] = C8_s[i8*8 + k];
#pragma unroll
    for (int j = 0; j < 8; ++j) {
      float dj = rdlane(c8[j], j);
      float rinv = rsqrtf(dj);
      if (i8 == j) rd8 = rinv;
      c8[j] *= rinv;
#pragma unroll
      for (int k = j+1; k < 8; ++k)
        c8[k] = fmaf(-rdlane(c8[j], k), c8[j], c8[k]);
    }
    float w8[8];
#pragma unroll
    for (int i = 0; i < 8; ++i) {
      float sacc = (i == i8) ? 1.0f : 0.0f;
#pragma unroll
      for (int k = 0; k < i; ++k)
        sacc = fmaf(-rdlane(c8[k], i), w8[k], sacc);
      w8[i] = sacc * rdlane(rd8, i);
    }
#pragma unroll
    for (int i = 0; i < 8; ++i) {
      float msum = 0.0f;
#pragma unroll
      for (int k = 0; k < 8; ++k)
        msum = fmaf(rdlane(w8[k], i), w8[k], msum);
      if (lam < 8) M8_s[i*8 + lam] = msum;
    }
  };

  // ================= step 0 =================
  {
    const float Pp = q0_r;
    const float h0 = m0_r / Pp + kt_r;
    if (w == 0) {
      const int r1 = lam >> 3, r2 = lam & 7;
      float acc = 0.0f;
#pragma unroll 4
      for (int l = 0; l < 64; ++l)
        acc = fmaf(Kt_s[l*8 + r1] * q0v_s[l], Kt_s[l*8 + r2], acc);
      C8_s[lam] = acc + (r1 == r2 ? 1.0f : 0.0f);
      chol8M8();
      float t8[8];
#pragma unroll
      for (int r = 0; r < 8; ++r) t8[r] = wsum(Pp * Kreg[r] * h0);
      float acc2 = 0.0f;
#pragma unroll
      for (int r1i = 0; r1i < 8; ++r1i) {
        float4 ma = *(const float4*)&M8_s[r1i*8];
        float4 mb = *(const float4*)&M8_s[r1i*8+4];
        float y = ma.x*t8[0]+ma.y*t8[1]+ma.z*t8[2]+ma.w*t8[3]
                + mb.x*t8[4]+mb.y*t8[5]+mb.z*t8[6]+mb.w*t8[7];
        acc2 = fmaf(Kreg[r1i], y, acc2);
      }
      float m0f = Pp*h0 - Pp*acc2;
      mf_s[lam] = m0f;
      outp[(size_t)b*L_ + lam] = m0f;
    }
    __syncthreads();

    const float qs0 = sqrtf(q0_r);
#pragma unroll
    for (int i = 0; i < 4; ++i) {
      const int s = 4*w + i;
      float zp = qs0 * wp2b[0][s*64 + lam];
      float v1[8];
#pragma unroll
      for (int r = 0; r < 8; ++r)
        v1[r] = wsum(Kreg[r] * zp) + wf_s[s*8 + r];
      float acc = 0.0f;
#pragma unroll
      for (int r1i = 0; r1i < 8; ++r1i) {
        float4 ma = *(const float4*)&M8_s[r1i*8];
        float4 mb = *(const float4*)&M8_s[r1i*8+4];
        float y = ma.x*v1[0]+ma.y*v1[1]+ma.z*v1[2]+ma.w*v1[3]
                + mb.x*v1[4]+mb.y*v1[5]+mb.z*v1[6]+mb.w*v1[7];
        acc = fmaf(Kreg[r1i], y, acc);
      }
      z_s[s*68 + lam] = zp - Pp*acc;   // z' excludes m_f (added in next dyn)
    }
  }
  __syncthreads();

  // ================= steps 1..T-1 =================
  for (int t = 1; t < T_; ++t) {
    const int cb = t & 1, nb = cb ^ 1;

    // per-lane K/k reload (global; hidden under P1, used from P2 on)
    {
      const float* kb = Kp + ((size_t)t*B_ + b)*(L_*R_) + lam*R_;
      float4 ka = *(const float4*)kb, kb4 = *(const float4*)(kb+4);
      Kreg[0]=ka.x;Kreg[1]=ka.y;Kreg[2]=ka.z;Kreg[3]=ka.w;
      Kreg[4]=kb4.x;Kreg[5]=kb4.y;Kreg[6]=kb4.z;Kreg[7]=kb4.w;
      kt_r = kp[((size_t)t*B_ + b)*L_ + lam];
    }

    // ---- P1: dyn on z = z' + mf (rows via conflict-free b128 broadcasts) ----
    float dmf = 0.0f;
#pragma unroll
    for (int j4 = 0; j4 < 16; ++j4) {
      float4 m4 = *(const float4*)&mf_s[4*j4];
      dmf = fmaf(m4.x, Areg[4*j4+0], dmf);
      dmf = fmaf(m4.y, Areg[4*j4+1], dmf);
      dmf = fmaf(m4.z, Areg[4*j4+2], dmf);
      dmf = fmaf(m4.w, Areg[4*j4+3], dmf);
    }
    const float mfl = mf_s[lam];
    float zn[5];
#pragma unroll
    for (int i = 0; i < 5; ++i) if (i < rcount) {
      const int s = rstart + i;
      float a0=0,a1=0,a2=0,a3=0;
#pragma unroll
      for (int j4 = 0; j4 < 16; ++j4) {
        float4 zb = *(const float4*)&z_s[s*68 + 4*j4];
        a0 = fmaf(zb.x, Areg[4*j4+0], a0);
        a1 = fmaf(zb.y, Areg[4*j4+1], a1);
        a2 = fmaf(zb.z, Areg[4*j4+2], a2);
        a3 = fmaf(zb.w, Areg[4*j4+3], a3);
      }
      float x = ((a0+a1)+(a2+a3)) + dmf;
      float e = __expf(2.0f*x);
      float tnh = 1.0f - 2.0f/(e + 1.0f);
      zn[i] = (z_s[s*68 + lam] + mfl) + 0.1f*tnh;
    }
    {
      float usum = 0.0f;
#pragma unroll
      for (int i = 0; i < 5; ++i) if (i < rcount) usum += zn[i];
      uni[w*68 + lam] = usum;
    }
    bar_lgkm();  // B1

    // ---- P0: async prefetch; drains at B2 (syncthreads) ----
    if (w == 0) {
      if (t < T_-1) {
#pragma unroll
        for (int m = 0; m < 4; ++m) {
          int f = m*256 + lam*4, s = f >> 5, c = f & 31;
          gload16(wp1p + (((size_t)t*S_ + s)*B_ + b)*S_ + c, &wp1b[nb][f]);
        }
      }
    } else if (w == 1 || w == 2) {
      if (t < T_-1) {
#pragma unroll
        for (int m = 0; m < 4; ++m) {
          int f = (w-1)*1024 + m*256 + lam*4, s = f >> 6, c = f & 63;
          gload16(wp2p + (((size_t)t*S_ + s)*B_ + b)*L_ + c, &wp2b[nb][f]);
        }
      }
    } else if (w == 3) {
      { int f = lam*4, s = f >> 3, c = f & 7;
        gload16(wfp + (((size_t)(t-1)*S_ + s)*B_ + b)*R_ + c, &wf_s[f]); }
#pragma unroll
      for (int m = 0; m < 2; ++m) {
        int f = m*256 + lam*4;
        gload16(Kp + ((size_t)t*B_ + b)*(L_*R_) + f, &Kt_s[f]);
      }
    }

    // ---- P2: m_p, M_c, KM = Mc^T K, tk = Mc^T k_t (DPP) ----
    float mp = 0.0f;
#pragma unroll
    for (int ww = 0; ww < 8; ++ww) mp += uni[ww*68 + lam];
    mp *= 0.03125f;
#pragma unroll
    for (int i = 0; i < 5; ++i) if (i < rcount) {
      const int s = rstart + i;
      float mcv = (zn[i] - mp) * 0.17677669529663689f;
      Mc_s[lam*33 + s] = mcv;
      float tkv = wredsum(mcv * kt_r);
      float kmv[8];
#pragma unroll
      for (int r = 0; r < 8; ++r) kmv[r] = wredsum(mcv * Kreg[r]);
      if (lam == 63) {
        tk_s[s] = tkv;
        *(float4*)&KM_s[s*8]   = make_float4(kmv[0],kmv[1],kmv[2],kmv[3]);
        *(float4*)&KM_s[s*8+4] = make_float4(kmv[4],kmv[5],kmv[6],kmv[7]);
      }
    }
    __syncthreads();  // B2 (full: drains prefetch vmcnt)

    // per-lane Mc row into registers (reused by P3 zprows and mkm)
    float mcrow[32];
#pragma unroll
    for (int s2 = 0; s2 < 32; ++s2) mcrow[s2] = Mc_s[lam*33 + s2];

    // ---- P3: zprows + wave0 {u, t8} + wave1 {C8, M8}; then mkm ----
    float zloc[5];
    float u_r = 0.0f, t8s[8];
#pragma unroll
    for (int r = 0; r < 8; ++r) t8s[r] = 0.0f;
#pragma unroll
    for (int i = 0; i < 5; ++i) if (i < rcount) {
      const int s = rstart + i;
      float acc = 0.0f;
#pragma unroll
      for (int p4 = 0; p4 < 32; p4 += 4) {
        float4 wb = *(const float4*)&wp1b[cb][s*32 + p4];
        acc = fmaf(mcrow[p4+0], wb.x, acc);
        acc = fmaf(mcrow[p4+1], wb.y, acc);
        acc = fmaf(mcrow[p4+2], wb.z, acc);
        acc = fmaf(mcrow[p4+3], wb.w, acc);
      }
      float zp = acc + qs_r * wp2b[cb][s*64 + lam];
      zloc[i] = zp;
      float vv[8];
#pragma unroll
      for (int r = 0; r < 8; ++r) vv[r] = wredsum(Kreg[r] * zp);
      if (lam == 63) {
        float4 wfa = *(const float4*)&wf_s[s*8];
        float4 wfb = *(const float4*)&wf_s[s*8+4];
        *(float4*)&v1t_s[s*8]   = make_float4(vv[0]+wfa.x, vv[1]+wfa.y,
                                              vv[2]+wfa.z, vv[3]+wfa.w);
        *(float4*)&v1t_s[s*8+4] = make_float4(vv[4]+wfb.x, vv[5]+wfb.y,
                                              vv[6]+wfb.z, vv[7]+wfb.w);
      }
    }
    if (w == 0) {
      // u = m_p + Mc tk + q k_t (Woodbury); t8 = K^T u (kept in wave0 regs)
      float mctk = 0.0f;
#pragma unroll
      for (int s4 = 0; s4 < 32; s4 += 4) {
        float4 tb = *(const float4*)&tk_s[s4];
        mctk = fmaf(mcrow[s4+0], tb.x, mctk);
        mctk = fmaf(mcrow[s4+1], tb.y, mctk);
        mctk = fmaf(mcrow[s4+2], tb.z, mctk);
        mctk = fmaf(mcrow[s4+3], tb.w, mctk);
      }
      u_r = mp + mctk + q_r * kt_r;
#pragma unroll
      for (int r = 0; r < 8; ++r)
        t8s[r] = rdlane(wredsum(Kreg[r] * u_r), 63);
    } else if (w == 1) {
      const int r1 = lam >> 3, r2 = lam & 7;
      float acc = 0.0f;
#pragma unroll 4
      for (int s = 0; s < 32; ++s)
        acc = fmaf(KM_s[s*8 + r1], KM_s[s*8 + r2], acc);
#pragma unroll 4
      for (int l = 0; l < 64; ++l)
        acc = fmaf(Kt_s[l*8 + r1] * qv_s[l], Kt_s[l*8 + r2], acc);
      C8_s[lam] = acc + (r1 == r2 ? 1.0f : 0.0f);
      chol8M8();
    }
    // mkm[r] = sum_s2 mcrow[s2]*KM[s2][r]  (per-lane; KM_s reads broadcast)
    float mkm[8];
#pragma unroll
    for (int r = 0; r < 8; ++r) mkm[r] = 0.0f;
#pragma unroll
    for (int s2 = 0; s2 < 32; ++s2) {
      float4 ka = *(const float4*)&KM_s[s2*8];
      float4 kb = *(const float4*)&KM_s[s2*8+4];
      const float mcl = mcrow[s2];
      mkm[0] = fmaf(mcl, ka.x, mkm[0]);
      mkm[1] = fmaf(mcl, ka.y, mkm[1]);
      mkm[2] = fmaf(mcl, ka.z, mkm[2]);
      mkm[3] = fmaf(mcl, ka.w, mkm[3]);
      mkm[4] = fmaf(mcl, kb.x, mkm[4]);
      mkm[5] = fmaf(mcl, kb.y, mkm[5]);
      mkm[6] = fmaf(mcl, kb.z, mkm[6]);
      mkm[7] = fmaf(mcl, kb.w, mkm[7]);
    }
    bar_lgkm();  // B3 (M8_s, v1t_s visible)

    // ---- P4: per row, y1 = M8 v1t; z -= MKM y1 + q*(K y1). No cross-lane. ----
#pragma unroll
    for (int i = 0; i < 5; ++i) if (i < rcount) {
      const int s = rstart + i;
      float4 va = *(const float4*)&v1t_s[s*8];
      float4 vb = *(const float4*)&v1t_s[s*8+4];
      float g = 0.0f, corr = 0.0f;
#pragma unroll
      for (int r = 0; r < 8; ++r) {
        float4 ma = *(const float4*)&M8_s[r*8];
        float4 mb = *(const float4*)&M8_s[r*8+4];
        float y = ma.x*va.x+ma.y*va.y+ma.z*va.z+ma.w*va.w
                + mb.x*vb.x+mb.y*vb.y+mb.z*vb.z+mb.w*vb.w;
        g    = fmaf(Kreg[r], y, g);
        corr = fmaf(mkm[r],  y, corr);
      }
      z_s[s*68 + lam] = zloc[i] - corr - q_r*g;   // z' (mf added next dyn)
    }
    if (w == 0) {   // mf tail: y8 = M8 t8; mf = u - MKM y8 - q*(K y8)
      float g = 0.0f, corr = 0.0f;
#pragma unroll
      for (int r = 0; r < 8; ++r) {
        float4 ma = *(const float4*)&M8_s[r*8];
        float4 mb = *(const float4*)&M8_s[r*8+4];
        float y = ma.x*t8s[0]+ma.y*t8s[1]+ma.z*t8s[2]+ma.w*t8s[3]
                + mb.x*t8s[4]+mb.y*t8s[5]+mb.z*t8s[6]+mb.w*t8s[7];
        g    = fmaf(Kreg[r], y, g);
        corr = fmaf(mkm[r],  y, corr);
      }
      const float mf_r = u_r - corr - q_r*g;
      mf_s[lam] = mf_r;
      outp[((size_t)t*B_ + b)*L_ + lam] = mf_r;
    }
    bar_lgkm();  // B4 (mf_s, z_s visible for next P1)
  }
}

extern "C" void kernel_launch(void* const* d_in, const int* in_sizes, int n_in,
                              void* d_out, int out_size, void* d_ws, size_t ws_size,
                              hipStream_t stream) {
  (void)in_sizes; (void)n_in; (void)out_size; (void)d_ws; (void)ws_size;
  nlf_kernel<<<dim3(B_), dim3(512), 0, stream>>>(
      (const float*)d_in[0], (const float*)d_in[1], (const float*)d_in[2],
      (const float*)d_in[3], (const float*)d_in[4], (const float*)d_in[5],
      (const float*)d_in[6], (const float*)d_in[7], (const float*)d_in[8],
      (const float*)d_in[9], (const float*)d_in[10], (float*)d_out);
}

// Round 11
// 5740.647 us; speedup vs baseline: 3.2827x; 2.9442x over previous
//
#include <hip/hip_runtime.h>
#include <cstdint>
#include <cstddef>

namespace {
constexpr int T_ = 500, S_ = 32, B_ = 128, L_ = 64, R_ = 8;

__device__ __forceinline__ float rdlane(float v, int l) {
  return __int_as_float(__builtin_amdgcn_readlane(__float_as_int(v), l));
}
template<int CTRL, int RM>
__device__ __forceinline__ float dppadd(float v) {
  int t = __builtin_amdgcn_update_dpp(0, __float_as_int(v), CTRL, RM, 0xf, false);
  return v + __int_as_float(t);
}
// full 64-lane sum; total lands in lane 63 (VALU-only, no DS)
__device__ __forceinline__ float wredsum(float v) {
  v = dppadd<0x111, 0xf>(v);   // row_shr:1
  v = dppadd<0x112, 0xf>(v);   // row_shr:2
  v = dppadd<0x114, 0xf>(v);   // row_shr:4
  v = dppadd<0x118, 0xf>(v);   // row_shr:8
  v = dppadd<0x142, 0xa>(v);   // row_bcast:15 -> rows 1,3
  v = dppadd<0x143, 0xc>(v);   // row_bcast:31 -> rows 2,3
  return v;
}
__device__ __forceinline__ float wsum(float v) {  // all-lanes result (step0 only)
  v += __shfl_xor(v, 1);  v += __shfl_xor(v, 2);  v += __shfl_xor(v, 4);
  v += __shfl_xor(v, 8);  v += __shfl_xor(v, 16); v += __shfl_xor(v, 32);
  return v;
}
__device__ __forceinline__ void gload16(const float* g, float* l) {
  __builtin_amdgcn_global_load_lds((const __attribute__((address_space(1))) uint32_t*)g,
                                   (__attribute__((address_space(3))) uint32_t*)l,
                                   16, 0, 0);
}
// barrier that drains LDS ops but lets global loads/stores ride (vmcnt untouched)
__device__ __forceinline__ void bar_lgkm() {
  asm volatile("s_waitcnt lgkmcnt(0)\n\ts_barrier" ::: "memory");
}
}  // namespace

// One block per batch element b. 512 threads = 8 waves, 4 ensemble rows/wave.
// mkm identity: Mc(Mc^T(K y)) = MKM y, mkm[r] = sum_s2 Mc[lam][s2]*KM[s2][r];
// M8 symmetric -> fold once per lane: kM8 = M8*Kreg, mkmM8 = M8*mkm, then
// each row's correction is two 8-term dots with v1t. No cross-lane in P4.
// Register discipline (R6/R9/R10 lesson: 512-thread blocks pin at 128 VGPRs):
// no mcrow cache; Mc_s stride 36 so row reads are ds_read_b128.
__global__ __launch_bounds__(512, 1) void nlf_kernel(
    const float* __restrict__ m0p, const float* __restrict__ q0p,
    const float* __restrict__ qp,  const float* __restrict__ kp,
    const float* __restrict__ Kp,  const float* __restrict__ Ap,
    const float* __restrict__ wp0p, const float* __restrict__ wf0p,
    const float* __restrict__ wp1p, const float* __restrict__ wp2p,
    const float* __restrict__ wfp,  float* __restrict__ outp)
{
  __shared__ __align__(16) float z_s[S_*68];      // carry z' (z - mf)
  __shared__ __align__(16) float Mc_s[L_*36];     // M_c[l][s], 16B-aligned rows
  __shared__ __align__(16) float uni[8*68];       // mp partial sums
  __shared__ __align__(16) float wp1b[2][S_*S_];
  __shared__ __align__(16) float wp2b[2][S_*L_];
  __shared__ __align__(16) float wf_s[S_*R_];
  __shared__ __align__(16) float Kt_s[L_*R_];
  __shared__ __align__(16) float v1t_s[S_*R_];
  __shared__ __align__(16) float KM_s[S_*R_];     // [s*8+r] = (Mc^T K)[s][r]
  __shared__ __align__(16) float M8_s[64];
  __shared__ __align__(16) float C8_s[64];
  __shared__ __align__(16) float tk_s[S_];        // Mc^T k_t
  __shared__ __align__(16) float t8_s[8];         // K^T u (wave0 P3 -> P4)
  __shared__ __align__(16) float mf_s[L_];
  __shared__ __align__(16) float qv_s[L_];
  __shared__ __align__(16) float q0v_s[L_];

  const int tid = threadIdx.x;
  const int lam = tid & 63;
  const int w   = tid >> 6;
  const int b   = blockIdx.x;

  float Areg[64];
#pragma unroll
  for (int j4 = 0; j4 < 16; ++j4) {
    float4 a4 = *(const float4*)(Ap + (size_t)lam*64 + j4*4);
    Areg[4*j4+0]=a4.x; Areg[4*j4+1]=a4.y; Areg[4*j4+2]=a4.z; Areg[4*j4+3]=a4.w;
  }
  const float q_r  = qp[lam];
  const float qs_r = sqrtf(q_r);
  const float q0_r = q0p[lam];
  const float m0_r = m0p[lam];
  if (tid < 64) { qv_s[tid] = q_r; q0v_s[tid] = q0_r; }

  float Kreg[8];
  {
    const float* kb = Kp + (size_t)b*(L_*R_) + lam*R_;
    float4 ka = *(const float4*)kb, kb4 = *(const float4*)(kb+4);
    Kreg[0]=ka.x;Kreg[1]=ka.y;Kreg[2]=ka.z;Kreg[3]=ka.w;
    Kreg[4]=kb4.x;Kreg[5]=kb4.y;Kreg[6]=kb4.z;Kreg[7]=kb4.w;
  }
  float kt_r = kp[(size_t)b*L_ + lam];

  // ---- prologue async loads ----
  if (w == 0) {                       // wp1[0] -> wp1b[1]
#pragma unroll
    for (int m = 0; m < 4; ++m) {
      int f = m*256 + lam*4, s = f >> 5, c = f & 31;
      gload16(wp1p + ((size_t)s*B_ + b)*S_ + c, &wp1b[1][f]);
    }
  } else if (w == 1 || w == 2) {      // wp2[0] -> wp2b[1]
#pragma unroll
    for (int m = 0; m < 4; ++m) {
      int f = (w-1)*1024 + m*256 + lam*4, s = f >> 6, c = f & 63;
      gload16(wp2p + ((size_t)s*B_ + b)*L_ + c, &wp2b[1][f]);
    }
  } else if (w == 3) {                // wf0 -> wf_s ; K[0] -> Kt_s
    { int f = lam*4, s = f >> 3, c = f & 7;
      gload16(wf0p + ((size_t)s*B_ + b)*R_ + c, &wf_s[f]); }
#pragma unroll
    for (int m = 0; m < 2; ++m) {
      int f = m*256 + lam*4;
      gload16(Kp + (size_t)b*(L_*R_) + f, &Kt_s[f]);
    }
  } else if (w == 4 || w == 5) {      // w_p0 -> wp2b[0]
#pragma unroll
    for (int m = 0; m < 4; ++m) {
      int f = (w-4)*1024 + m*256 + lam*4, s = f >> 6, c = f & 63;
      gload16(wp0p + ((size_t)s*B_ + b)*L_ + c, &wp2b[0][f]);
    }
  }
  __syncthreads();

  // 8x8 SPD: C8_s -> M8_s = inv(C8) via in-register Cholesky (rows in lanes 0-7)
  auto chol8M8 = [&]() {
    const int i8 = lam & 7;
    float c8[8], rd8 = 0.0f;
#pragma unroll
    for (int k = 0; k < 8; ++k) c8[k] = C8_s[i8*8 + k];
#pragma unroll
    for (int j = 0; j < 8; ++j) {
      float dj = rdlane(c8[j], j);
      float rinv = rsqrtf(dj);
      if (i8 == j) rd8 = rinv;
      c8[j] *= rinv;
#pragma unroll
      for (int k = j+1; k < 8; ++k)
        c8[k] = fmaf(-rdlane(c8[j], k), c8[j], c8[k]);
    }
    float w8[8];
#pragma unroll
    for (int i = 0; i < 8; ++i) {
      float sacc = (i == i8) ? 1.0f : 0.0f;
#pragma unroll
      for (int k = 0; k < i; ++k)
        sacc = fmaf(-rdlane(c8[k], i), w8[k], sacc);
      w8[i] = sacc * rdlane(rd8, i);
    }
#pragma unroll
    for (int i = 0; i < 8; ++i) {
      float msum = 0.0f;
#pragma unroll
      for (int k = 0; k < 8; ++k)
        msum = fmaf(rdlane(w8[k], i), w8[k], msum);
      if (lam < 8) M8_s[i*8 + lam] = msum;
    }
  };

  // ================= step 0 =================
  {
    const float Pp = q0_r;
    const float h0 = m0_r / Pp + kt_r;
    if (w == 0) {
      const int r1 = lam >> 3, r2 = lam & 7;
      float acc = 0.0f;
#pragma unroll 4
      for (int l = 0; l < 64; ++l)
        acc = fmaf(Kt_s[l*8 + r1] * q0v_s[l], Kt_s[l*8 + r2], acc);
      C8_s[lam] = acc + (r1 == r2 ? 1.0f : 0.0f);
      chol8M8();
      float t8[8];
#pragma unroll
      for (int r = 0; r < 8; ++r) t8[r] = wsum(Pp * Kreg[r] * h0);
      float acc2 = 0.0f;
#pragma unroll
      for (int r1i = 0; r1i < 8; ++r1i) {
        float4 ma = *(const float4*)&M8_s[r1i*8];
        float4 mb = *(const float4*)&M8_s[r1i*8+4];
        float y = ma.x*t8[0]+ma.y*t8[1]+ma.z*t8[2]+ma.w*t8[3]
                + mb.x*t8[4]+mb.y*t8[5]+mb.z*t8[6]+mb.w*t8[7];
        acc2 = fmaf(Kreg[r1i], y, acc2);
      }
      float m0f = Pp*h0 - Pp*acc2;
      mf_s[lam] = m0f;
      outp[(size_t)b*L_ + lam] = m0f;
    }
    __syncthreads();

    const float qs0 = sqrtf(q0_r);
#pragma unroll
    for (int i = 0; i < 4; ++i) {
      const int s = 4*w + i;
      float zp = qs0 * wp2b[0][s*64 + lam];
      float v1[8];
#pragma unroll
      for (int r = 0; r < 8; ++r)
        v1[r] = wsum(Kreg[r] * zp) + wf_s[s*8 + r];
      float acc = 0.0f;
#pragma unroll
      for (int r1i = 0; r1i < 8; ++r1i) {
        float4 ma = *(const float4*)&M8_s[r1i*8];
        float4 mb = *(const float4*)&M8_s[r1i*8+4];
        float y = ma.x*v1[0]+ma.y*v1[1]+ma.z*v1[2]+ma.w*v1[3]
                + mb.x*v1[4]+mb.y*v1[5]+mb.z*v1[6]+mb.w*v1[7];
        acc = fmaf(Kreg[r1i], y, acc);
      }
      z_s[s*68 + lam] = zp - Pp*acc;   // z' excludes m_f (added in next dyn)
    }
  }
  __syncthreads();

  // ================= steps 1..T-1 =================
  for (int t = 1; t < T_; ++t) {
    const int cb = t & 1, nb = cb ^ 1;

    // per-lane K/k reload (global; hidden under P1, used from P2 on)
    {
      const float* kb = Kp + ((size_t)t*B_ + b)*(L_*R_) + lam*R_;
      float4 ka = *(const float4*)kb, kb4 = *(const float4*)(kb+4);
      Kreg[0]=ka.x;Kreg[1]=ka.y;Kreg[2]=ka.z;Kreg[3]=ka.w;
      Kreg[4]=kb4.x;Kreg[5]=kb4.y;Kreg[6]=kb4.z;Kreg[7]=kb4.w;
      kt_r = kp[((size_t)t*B_ + b)*L_ + lam];
    }

    // ---- P1: dyn on z = z' + mf (rows via conflict-free b128 broadcasts) ----
    float dmf = 0.0f;
#pragma unroll
    for (int j4 = 0; j4 < 16; ++j4) {
      float4 m4 = *(const float4*)&mf_s[4*j4];
      dmf = fmaf(m4.x, Areg[4*j4+0], dmf);
      dmf = fmaf(m4.y, Areg[4*j4+1], dmf);
      dmf = fmaf(m4.z, Areg[4*j4+2], dmf);
      dmf = fmaf(m4.w, Areg[4*j4+3], dmf);
    }
    const float mfl = mf_s[lam];
    float zn[4];
#pragma unroll
    for (int i = 0; i < 4; ++i) {
      const int s = 4*w + i;
      float a0=0,a1=0,a2=0,a3=0;
#pragma unroll
      for (int j4 = 0; j4 < 16; ++j4) {
        float4 zb = *(const float4*)&z_s[s*68 + 4*j4];
        a0 = fmaf(zb.x, Areg[4*j4+0], a0);
        a1 = fmaf(zb.y, Areg[4*j4+1], a1);
        a2 = fmaf(zb.z, Areg[4*j4+2], a2);
        a3 = fmaf(zb.w, Areg[4*j4+3], a3);
      }
      float x = ((a0+a1)+(a2+a3)) + dmf;
      float e = __expf(2.0f*x);
      float tnh = 1.0f - 2.0f/(e + 1.0f);
      zn[i] = (z_s[s*68 + lam] + mfl) + 0.1f*tnh;
    }
    uni[w*68 + lam] = zn[0]+zn[1]+zn[2]+zn[3];
    bar_lgkm();  // B1

    // ---- P0: async prefetch; drains at B2 (syncthreads) ----
    if (w == 0) {
      if (t < T_-1) {
#pragma unroll
        for (int m = 0; m < 4; ++m) {
          int f = m*256 + lam*4, s = f >> 5, c = f & 31;
          gload16(wp1p + (((size_t)t*S_ + s)*B_ + b)*S_ + c, &wp1b[nb][f]);
        }
      }
    } else if (w == 1 || w == 2) {
      if (t < T_-1) {
#pragma unroll
        for (int m = 0; m < 4; ++m) {
          int f = (w-1)*1024 + m*256 + lam*4, s = f >> 6, c = f & 63;
          gload16(wp2p + (((size_t)t*S_ + s)*B_ + b)*L_ + c, &wp2b[nb][f]);
        }
      }
    } else if (w == 3) {
      { int f = lam*4, s = f >> 3, c = f & 7;
        gload16(wfp + (((size_t)(t-1)*S_ + s)*B_ + b)*R_ + c, &wf_s[f]); }
#pragma unroll
      for (int m = 0; m < 2; ++m) {
        int f = m*256 + lam*4;
        gload16(Kp + ((size_t)t*B_ + b)*(L_*R_) + f, &Kt_s[f]);
      }
    }

    // ---- P2: m_p, M_c, KM = Mc^T K, tk = Mc^T k_t (DPP) ----
    float mp = 0.0f;
#pragma unroll
    for (int ww = 0; ww < 8; ++ww) mp += uni[ww*68 + lam];
    mp *= 0.03125f;
#pragma unroll
    for (int i = 0; i < 4; ++i) {
      const int s = 4*w + i;
      float mcv = (zn[i] - mp) * 0.17677669529663689f;
      Mc_s[lam*36 + s] = mcv;
      float tkv = wredsum(mcv * kt_r);
      float kmv[8];
#pragma unroll
      for (int r = 0; r < 8; ++r) kmv[r] = wredsum(mcv * Kreg[r]);
      if (lam == 63) {
        tk_s[s] = tkv;
        *(float4*)&KM_s[s*8]   = make_float4(kmv[0],kmv[1],kmv[2],kmv[3]);
        *(float4*)&KM_s[s*8+4] = make_float4(kmv[4],kmv[5],kmv[6],kmv[7]);
      }
    }
    __syncthreads();  // B2 (full: drains prefetch vmcnt)

    // ---- P3: zprows + wave0 {u, t8 -> LDS} + wave1 {C8, M8}; then mkm ----
    float zloc[4];
    float u_r = 0.0f;
#pragma unroll
    for (int i = 0; i < 4; ++i) {
      const int s = 4*w + i;
      float acc = 0.0f;
#pragma unroll
      for (int p4 = 0; p4 < 32; p4 += 4) {
        float4 mc4 = *(const float4*)&Mc_s[lam*36 + p4];
        float4 wb  = *(const float4*)&wp1b[cb][s*32 + p4];
        acc = fmaf(mc4.x, wb.x, acc);
        acc = fmaf(mc4.y, wb.y, acc);
        acc = fmaf(mc4.z, wb.z, acc);
        acc = fmaf(mc4.w, wb.w, acc);
      }
      float zp = acc + qs_r * wp2b[cb][s*64 + lam];
      zloc[i] = zp;
      float vv[8];
#pragma unroll
      for (int r = 0; r < 8; ++r) vv[r] = wredsum(Kreg[r] * zp);
      if (lam == 63) {
        float4 wfa = *(const float4*)&wf_s[s*8];
        float4 wfb = *(const float4*)&wf_s[s*8+4];
        *(float4*)&v1t_s[s*8]   = make_float4(vv[0]+wfa.x, vv[1]+wfa.y,
                                              vv[2]+wfa.z, vv[3]+wfa.w);
        *(float4*)&v1t_s[s*8+4] = make_float4(vv[4]+wfb.x, vv[5]+wfb.y,
                                              vv[6]+wfb.z, vv[7]+wfb.w);
      }
    }
    if (w == 0) {
      // u = m_p + Mc tk + q k_t (Woodbury); t8 = K^T u -> LDS
      float mctk = 0.0f;
#pragma unroll
      for (int s4 = 0; s4 < 32; s4 += 4) {
        float4 mc4 = *(const float4*)&Mc_s[lam*36 + s4];
        float4 tb  = *(const float4*)&tk_s[s4];
        mctk = fmaf(mc4.x, tb.x, mctk);
        mctk = fmaf(mc4.y, tb.y, mctk);
        mctk = fmaf(mc4.z, tb.z, mctk);
        mctk = fmaf(mc4.w, tb.w, mctk);
      }
      u_r = mp + mctk + q_r * kt_r;
      float vv[8];
#pragma unroll
      for (int r = 0; r < 8; ++r) vv[r] = wredsum(Kreg[r] * u_r);
      if (lam == 63) {
        *(float4*)&t8_s[0] = make_float4(vv[0],vv[1],vv[2],vv[3]);
        *(float4*)&t8_s[4] = make_float4(vv[4],vv[5],vv[6],vv[7]);
      }
    } else if (w == 1) {
      const int r1 = lam >> 3, r2 = lam & 7;
      float acc = 0.0f;
#pragma unroll 4
      for (int s = 0; s < 32; ++s)
        acc = fmaf(KM_s[s*8 + r1], KM_s[s*8 + r2], acc);
#pragma unroll 4
      for (int l = 0; l < 64; ++l)
        acc = fmaf(Kt_s[l*8 + r1] * qv_s[l], Kt_s[l*8 + r2], acc);
      C8_s[lam] = acc + (r1 == r2 ? 1.0f : 0.0f);
      chol8M8();
    }
    // mkm[r] = sum_s2 Mc[lam][s2]*KM[s2][r] (Mc row b128, KM broadcast b128)
    float mkm[8];
#pragma unroll
    for (int r = 0; r < 8; ++r) mkm[r] = 0.0f;
#pragma unroll
    for (int s4 = 0; s4 < 32; s4 += 4) {
      float4 mc4 = *(const float4*)&Mc_s[lam*36 + s4];
#pragma unroll
      for (int ii = 0; ii < 4; ++ii) {
        const float mcl = (ii==0)?mc4.x:(ii==1)?mc4.y:(ii==2)?mc4.z:mc4.w;
        float4 ka = *(const float4*)&KM_s[(s4+ii)*8];
        float4 kb = *(const float4*)&KM_s[(s4+ii)*8+4];
        mkm[0] = fmaf(mcl, ka.x, mkm[0]);
        mkm[1] = fmaf(mcl, ka.y, mkm[1]);
        mkm[2] = fmaf(mcl, ka.z, mkm[2]);
        mkm[3] = fmaf(mcl, ka.w, mkm[3]);
        mkm[4] = fmaf(mcl, kb.x, mkm[4]);
        mkm[5] = fmaf(mcl, kb.y, mkm[5]);
        mkm[6] = fmaf(mcl, kb.z, mkm[6]);
        mkm[7] = fmaf(mcl, kb.w, mkm[7]);
      }
    }
    bar_lgkm();  // B3 (M8_s, v1t_s, t8_s visible)

    // ---- P4: fold M8 once per lane (symmetric): kM8 = M8 K, mkmM8 = M8 mkm ----
    float kM8[8], mkmM8[8];
#pragma unroll
    for (int j = 0; j < 8; ++j) { kM8[j] = 0.0f; mkmM8[j] = 0.0f; }
#pragma unroll
    for (int r = 0; r < 8; ++r) {
      float4 ma = *(const float4*)&M8_s[r*8];
      float4 mb = *(const float4*)&M8_s[r*8+4];
      const float kr = Kreg[r], mr = mkm[r];
      kM8[0] = fmaf(kr, ma.x, kM8[0]);   mkmM8[0] = fmaf(mr, ma.x, mkmM8[0]);
      kM8[1] = fmaf(kr, ma.y, kM8[1]);   mkmM8[1] = fmaf(mr, ma.y, mkmM8[1]);
      kM8[2] = fmaf(kr, ma.z, kM8[2]);   mkmM8[2] = fmaf(mr, ma.z, mkmM8[2]);
      kM8[3] = fmaf(kr, ma.w, kM8[3]);   mkmM8[3] = fmaf(mr, ma.w, mkmM8[3]);
      kM8[4] = fmaf(kr, mb.x, kM8[4]);   mkmM8[4] = fmaf(mr, mb.x, mkmM8[4]);
      kM8[5] = fmaf(kr, mb.y, kM8[5]);   mkmM8[5] = fmaf(mr, mb.y, mkmM8[5]);
      kM8[6] = fmaf(kr, mb.z, kM8[6]);   mkmM8[6] = fmaf(mr, mb.z, mkmM8[6]);
      kM8[7] = fmaf(kr, mb.w, kM8[7]);   mkmM8[7] = fmaf(mr, mb.w, mkmM8[7]);
    }
    // per row: g = kM8 . v1t, corr = mkmM8 . v1t  (2 b128 + 16 FMA)
#pragma unroll
    for (int i = 0; i < 4; ++i) {
      const int s = 4*w + i;
      float4 va = *(const float4*)&v1t_s[s*8];
      float4 vb = *(const float4*)&v1t_s[s*8+4];
      float g    = kM8[0]*va.x + kM8[1]*va.y + kM8[2]*va.z + kM8[3]*va.w
                 + kM8[4]*vb.x + kM8[5]*vb.y + kM8[6]*vb.z + kM8[7]*vb.w;
      float corr = mkmM8[0]*va.x + mkmM8[1]*va.y + mkmM8[2]*va.z + mkmM8[3]*va.w
                 + mkmM8[4]*vb.x + mkmM8[5]*vb.y + mkmM8[6]*vb.z + mkmM8[7]*vb.w;
      z_s[s*68 + lam] = zloc[i] - corr - q_r*g;   // z' (mf added next dyn)
    }
    if (w == 0) {   // mf tail: t8 from LDS; mf = u - mkmM8.t8 - q*(kM8.t8)
      float4 ta = *(const float4*)&t8_s[0];
      float4 tb = *(const float4*)&t8_s[4];
      float g    = kM8[0]*ta.x + kM8[1]*ta.y + kM8[2]*ta.z + kM8[3]*ta.w
                 + kM8[4]*tb.x + kM8[5]*tb.y + kM8[6]*tb.z + kM8[7]*tb.w;
      float corr = mkmM8[0]*ta.x + mkmM8[1]*ta.y + mkmM8[2]*ta.z + mkmM8[3]*ta.w
                 + mkmM8[4]*tb.x + mkmM8[5]*tb.y + mkmM8[6]*tb.z + mkmM8[7]*tb.w;
      const float mf_r = u_r - corr - q_r*g;
      mf_s[lam] = mf_r;
      outp[((size_t)t*B_ + b)*L_ + lam] = mf_r;
    }
    bar_lgkm();  // B4 (mf_s, z_s visible for next P1)
  }
}

extern "C" void kernel_launch(void* const* d_in, const int* in_sizes, int n_in,
                              void* d_out, int out_size, void* d_ws, size_t ws_size,
                              hipStream_t stream) {
  (void)in_sizes; (void)n_in; (void)out_size; (void)d_ws; (void)ws_size;
  nlf_kernel<<<dim3(B_), dim3(512), 0, stream>>>(
      (const float*)d_in[0], (const float*)d_in[1], (const float*)d_in[2],
      (const float*)d_in[3], (const float*)d_in[4], (const float*)d_in[5],
      (const float*)d_in[6], (const float*)d_in[7], (const float*)d_in[8],
      (const float*)d_in[9], (const float*)d_in[10], (float*)d_out);
}